// Round 10
// baseline (122.412 us; speedup 1.0000x reference)
//
#include <hip/hip_runtime.h>
#include <hip/hip_bf16.h>

typedef __attribute__((ext_vector_type(8)))  short short8;
typedef __attribute__((ext_vector_type(16))) float f32x16;

#define DIM_D 256
#define DIM_O 256
#define DIM_K 8
#define BM 128                    // 4 waves x 32 rows
#define NCHUNK 16                 // 16 chunks of 16 d-values

__device__ __forceinline__ unsigned short f2bf(float f) {
    union { float f; unsigned int u; } v; v.f = f;
    unsigned int u = v.u;
    u += 0x7fffu + ((u >> 16) & 1u);   // round-to-nearest-even
    return (unsigned short)(u >> 16);
}

// v_cvt_pk_bf16_f32: dst.lo = bf16(lo), dst.hi = bf16(hi), RNE — 1 instr
__device__ __forceinline__ unsigned int cvt_pk_bf16(float lo, float hi) {
    unsigned int r;
    asm("v_cvt_pk_bf16_f32 %0, %1, %2" : "=v"(r) : "v"(lo), "v"(hi));
    return r;
}

// Pack cheby_coeffs (O,D,K) f32 -> bf16 in 32x32x16 MFMA B-fragment order:
// wp[s][ct][lane][j] = c[o = ct*32 + (l&31)][d = s*2 + (l>>5)][k = j]
// (B-frag: col = lane&31, k = (lane>>5)*8 + j) — layout verified rounds 8/9.
__global__ void pack_w_kernel(const float* __restrict__ coeffs,
                              unsigned short* __restrict__ wp) {
    int e = blockIdx.x * 256 + threadIdx.x;      // 0 .. 524287
    int j  = e & 7;
    int l  = (e >> 3) & 63;
    int ct = (e >> 9) & 7;
    int s  = e >> 12;                            // 0..127
    int o = ct * 32 + (l & 31);
    int d = s * 2 + (l >> 5);
    wp[e] = f2bf(coeffs[((size_t)o * DIM_D + d) * DIM_K + j]);
}

// tanh + Chebyshev recurrence -> one 32x32x16 A-fragment (T0..T7) in regs
__device__ __forceinline__ short8 cheb_frag(float xs) {
    // tanh(x) = 1 - 2/(e^{2x}+1); |x| <= ~6 for randn inputs, no clamp
    float e2 = __expf(2.f * xs);
    float r  = __builtin_amdgcn_rcpf(e2 + 1.f);
    float T1 = __builtin_fmaf(-2.f, r, 1.f);
    float tx = T1 + T1;
    float T2 = __builtin_fmaf(tx, T1, -1.f);
    float T3 = __builtin_fmaf(tx, T2, -T1);
    float T4 = __builtin_fmaf(tx, T3, -T2);
    float T5 = __builtin_fmaf(tx, T4, -T3);
    float T6 = __builtin_fmaf(tx, T5, -T4);
    float T7 = __builtin_fmaf(tx, T6, -T5);
    union { unsigned int u[4]; short8 s; } tv;
    tv.u[0] = cvt_pk_bf16(1.f, T1);
    tv.u[1] = cvt_pk_bf16(T2, T3);
    tv.u[2] = cvt_pk_bf16(T4, T5);
    tv.u[3] = cvt_pk_bf16(T6, T7);
    return tv.s;
}

// LDS-free, row-split waves: wave w owns rows [w*32, w*32+32) x all 256 cols.
// Lane l computes its own A-frag: row = l&31, d = 2s + (l>>5) — no redundancy.
__global__ __launch_bounds__(256, 2) void cfkan_kernel(
    const float* __restrict__ x,
    const unsigned short* __restrict__ wp,
    const float* __restrict__ bias,
    float* __restrict__ y)
{
    const int t = threadIdx.x;
    const int w = t >> 6;            // wave 0..3 -> rows [32w, 32w+32)
    const int l = t & 63;
    const int m = l & 31;            // A row / B,C col within 32-tile
    const int h = l >> 5;            // k-half: d-parity
    const int row = blockIdx.x * BM + w * 32 + m;
    const short8* wp8 = (const short8*)wp;
    const float* xr = x + (size_t)row * DIM_D;

    f32x16 acc[8];
    #pragma unroll
    for (int ct = 0; ct < 8; ++ct)
        #pragma unroll
        for (int q = 0; q < 16; ++q)
            acc[ct][q] = 0.f;

    // ---- prologue: x(chunk0) + B(step0) ----
    float2 xn2[8];
    #pragma unroll
    for (int s = 0; s < 8; ++s)
        xn2[s] = *(const float2*)(xr + 2 * s);
    short8 bc[8];
    #pragma unroll
    for (int ct = 0; ct < 8; ++ct)
        bc[ct] = wp8[(size_t)ct * 64 + l];

    // ---- main loop: free-running, no LDS; 8 k-steps per chunk ----
    #pragma unroll 1
    for (int c = 0; c < NCHUNK; ++c) {
        // select this chunk's x component (d-parity h), prefetch next chunk
        float xs[8];
        #pragma unroll
        for (int s = 0; s < 8; ++s)
            xs[s] = h ? xn2[s].y : xn2[s].x;
        if (c + 1 < NCHUNK) {
            #pragma unroll
            for (int s = 0; s < 8; ++s)
                xn2[s] = *(const float2*)(xr + (c + 1) * 16 + 2 * s);
        }

        #pragma unroll
        for (int s = 0; s < 8; ++s) {
            // B for next step (double-buffered; renamed by unroll)
            const int sgn = (c * 8 + s + 1) & 127;   // wraps at end; harmless
            short8 bn[8];
            #pragma unroll
            for (int ct = 0; ct < 8; ++ct)
                bn[ct] = wp8[((size_t)sgn * 8 + ct) * 64 + l];

            short8 a = cheb_frag(xs[s]);

            __builtin_amdgcn_s_setprio(1);
            #pragma unroll
            for (int ct = 0; ct < 8; ++ct)
                acc[ct] = __builtin_amdgcn_mfma_f32_32x32x16_bf16(
                    a, bc[ct], acc[ct], 0, 0, 0);
            __builtin_amdgcn_s_setprio(0);

            #pragma unroll
            for (int ct = 0; ct < 8; ++ct)
                bc[ct] = bn[ct];
        }
        // bare re-phase barrier (no memory drain needed — nothing shared);
        // keeps the 4 waves' B-streams L1-coherent
        __builtin_amdgcn_s_barrier();
    }

    // ---- epilogue: add bias, store f32 ----
    // C/D 32x32: col = lane&31, row = (q&3) + 8*(q>>2) + 4*(lane>>5)
    #pragma unroll
    for (int ct = 0; ct < 8; ++ct) {
        const int col = ct * 32 + m;
        const float bv = bias[col];
        #pragma unroll
        for (int q = 0; q < 16; ++q) {
            const int grow = (row & ~31) + (q & 3) + 8 * (q >> 2) + 4 * h;
            y[(size_t)grow * DIM_O + col] = acc[ct][q] + bv;
        }
    }
}

extern "C" void kernel_launch(void* const* d_in, const int* in_sizes, int n_in,
                              void* d_out, int out_size, void* d_ws, size_t ws_size,
                              hipStream_t stream) {
    const float* x      = (const float*)d_in[0];
    const float* coeffs = (const float*)d_in[1];
    const float* bias   = (const float*)d_in[2];
    float* y = (float*)d_out;
    unsigned short* wp = (unsigned short*)d_ws;   // 2048*256 bf16 = 1 MB

    const int n_tokens = in_sizes[0] / DIM_D;     // 65536

    pack_w_kernel<<<(DIM_O * DIM_D * DIM_K) / 256, 256, 0, stream>>>(coeffs, wp);
    cfkan_kernel<<<n_tokens / BM, 256, 0, stream>>>(x, wp, bias, y);
}

// Round 11
// 84.285 us; speedup vs baseline: 1.4524x; 1.4524x over previous
//
#include <hip/hip_runtime.h>
#include <hip/hip_bf16.h>

typedef __attribute__((ext_vector_type(4)))  int   i32x4;
typedef __attribute__((ext_vector_type(16))) int   i32x16;

#define DIM_D 256
#define DIM_O 256
#define DIM_K 8
#define BM 128
#define NCHUNK 16                 // 16 chunks of 16 d-values
#define NSTEP 4                   // 4 K=32 steps per chunk (4 d's each)
#define MAGIC 12582912.f          // 1.5 * 2^23 : fma+bit-extract = rint to int8

// ---- kernel 0: s_c = max|coeffs| via wave-reduce + atomicMax ----
__global__ void kmax_kernel(const float* __restrict__ coeffs,
                            unsigned int* __restrict__ smax) {
    int t = blockIdx.x * 256 + threadIdx.x;       // 512 blocks
    const float4 v = *(const float4*)(coeffs + (size_t)t * 4);
    float m = fmaxf(fmaxf(fabsf(v.x), fabsf(v.y)),
                    fmaxf(fabsf(v.z), fabsf(v.w)));
    #pragma unroll
    for (int d = 32; d >= 1; d >>= 1)
        m = fmaxf(m, __shfl_xor(m, d));
    if ((threadIdx.x & 63) == 0)
        atomicMax(smax, __float_as_uint(m));      // |c|>=0: bits monotone
}

// ---- kernel 1: pack coeffs -> i8 in 32x32x32 MFMA B-fragment order ----
// wp[s][ct][lane][j] = q(c[o=ct*32+(l&31)][d=4s+(l>>5)*2+(j>>3)][k=j&7])
__global__ void pack_w_kernel(const float* __restrict__ coeffs,
                              const unsigned int* __restrict__ smax,
                              unsigned int* __restrict__ wp) {
    const float sc  = __uint_as_float(*smax);
    const float inv = 127.0f / sc;
    int f = blockIdx.x * 256 + threadIdx.x;       // 0..131071, 4 bytes each
    int e  = f * 4;
    int j0 = e & 15;                              // 0,4,8,12
    int l  = (e >> 4) & 63;
    int ct = (e >> 10) & 7;
    int s  = e >> 13;                             // 0..63
    int o = ct * 32 + (l & 31);
    int d = 4 * s + (l >> 5) * 2 + (j0 >> 3);
    int k = j0 & 7;                               // 0 or 4; +0..3 consecutive
    const float4 c4 = *(const float4*)(coeffs + ((size_t)o * DIM_D + d) * DIM_K + k);
    unsigned q0 = __float_as_uint(__builtin_fmaf(c4.x, inv, MAGIC)) & 0xFF;
    unsigned q1 = __float_as_uint(__builtin_fmaf(c4.y, inv, MAGIC)) & 0xFF;
    unsigned q2 = __float_as_uint(__builtin_fmaf(c4.z, inv, MAGIC)) & 0xFF;
    unsigned q3 = __float_as_uint(__builtin_fmaf(c4.w, inv, MAGIC)) & 0xFF;
    wp[f] = q0 | (q1 << 8) | (q2 << 16) | (q3 << 24);
}

// tanh + Chebyshev recurrence -> 8 orders quantized to 8 bytes (2 u32)
__device__ __forceinline__ void cheb_q8(float xs, unsigned int* o2) {
    float e2 = __expf(2.f * xs);
    float r  = __builtin_amdgcn_rcpf(e2 + 1.f);
    float T1 = __builtin_fmaf(-2.f, r, 1.f);
    float tx = T1 + T1;
    float T2 = __builtin_fmaf(tx, T1, -1.f);
    float T3 = __builtin_fmaf(tx, T2, -T1);
    float T4 = __builtin_fmaf(tx, T3, -T2);
    float T5 = __builtin_fmaf(tx, T4, -T3);
    float T6 = __builtin_fmaf(tx, T5, -T4);
    float T7 = __builtin_fmaf(tx, T6, -T5);
    unsigned q1 = __float_as_uint(__builtin_fmaf(T1, 127.f, MAGIC)) & 0xFF;
    unsigned q2 = __float_as_uint(__builtin_fmaf(T2, 127.f, MAGIC)) & 0xFF;
    unsigned q3 = __float_as_uint(__builtin_fmaf(T3, 127.f, MAGIC)) & 0xFF;
    unsigned q4 = __float_as_uint(__builtin_fmaf(T4, 127.f, MAGIC)) & 0xFF;
    unsigned q5 = __float_as_uint(__builtin_fmaf(T5, 127.f, MAGIC)) & 0xFF;
    unsigned q6 = __float_as_uint(__builtin_fmaf(T6, 127.f, MAGIC)) & 0xFF;
    unsigned q7 = __float_as_uint(__builtin_fmaf(T7, 127.f, MAGIC)) & 0xFF;
    o2[0] = 127u | (q1 << 8) | (q2 << 16) | (q3 << 24);   // T0 = 1 -> 127
    o2[1] = q4 | (q5 << 8) | (q6 << 16) | (q7 << 24);
}

__global__ __launch_bounds__(256, 2) void cfkan_kernel(
    const float* __restrict__ x,
    const i32x4* __restrict__ wp8,
    const unsigned int* __restrict__ smax,
    const float* __restrict__ bias,
    float* __restrict__ y)
{
    // double-buffered i8 A tile: [row][8 slots of 16B], slot XOR-swizzle; 32 KB
    __shared__ unsigned char Abuf[2][BM][128];

    const int t = threadIdx.x;
    const int w = t >> 6;            // wave 0..3 -> output cols [64w, 64w+64)
    const int l = t & 63;
    const int m = l & 31;            // A row / B,C col within 32-tile
    const int h = l >> 5;            // k-half: d-pair parity
    const int row0 = blockIdx.x * BM;
    const float sf = __uint_as_float(*smax) * (1.f / 16129.f); // sc/127^2

    i32x16 acc[4][2];
    #pragma unroll
    for (int rt = 0; rt < 4; ++rt)
        #pragma unroll
        for (int ct = 0; ct < 2; ++ct)
            #pragma unroll
            for (int q = 0; q < 16; ++q)
                acc[rt][ct][q] = 0;

    const int lrow = t >> 1;         // 0..127 (row this thread stages)
    const int half = t & 1;          // which 8 of the 16 chunk-d's
    const float* xrow = x + (size_t)(row0 + lrow) * DIM_D + half * 8;

// A-frag read: step S, lane -> rows rt*32+m, slot (2S+h), XOR by row&7
#define READA(DST, AB, S) do {                                             \
    const int _so = (((2 * (S) + h) ^ (m & 7)) * 16);                      \
    DST[0] = *(const i32x4*)&AB[      m][_so];                             \
    DST[1] = *(const i32x4*)&AB[ 32 + m][_so];                             \
    DST[2] = *(const i32x4*)&AB[ 64 + m][_so];                             \
    DST[3] = *(const i32x4*)&AB[ 96 + m][_so];                             \
} while (0)
#define LOADB2(DST, SG) do {                                               \
    DST[0] = wp8[((SG) * 8 + w * 2 + 0) * 64 + l];                         \
    DST[1] = wp8[((SG) * 8 + w * 2 + 1) * 64 + l];                         \
} while (0)
// stage d-pair {2S, 2S+1} of next chunk: one swizzled ds_write_b128
#define STAGE2(ANX, S, X0, X1) do {                                        \
    union { unsigned int u[4]; i32x4 v; } _tv;                             \
    cheb_q8(X0, &_tv.u[0]);                                                \
    cheb_q8(X1, &_tv.u[2]);                                                \
    *(i32x4*)&ANX[lrow][(((half * 4 + (S)) ^ (lrow & 7)) * 16)] = _tv.v;   \
} while (0)
// barrier draining ONLY LDS ops; global loads stay in flight (T4)
#define SOFT_BARRIER() do {                                                \
    asm volatile("s_waitcnt lgkmcnt(0)" ::: "memory");                     \
    __builtin_amdgcn_s_barrier();                                          \
    __builtin_amdgcn_sched_barrier(0);                                     \
} while (0)

    // ---- prologue: stage chunk 0; preload x(chunk1) + B(step0) ----
    float xv[8];
    {
        float4 a0 = *(const float4*)xrow;
        float4 a1 = *(const float4*)(xrow + 4);
        float xs[8] = {a0.x, a0.y, a0.z, a0.w, a1.x, a1.y, a1.z, a1.w};
        #pragma unroll
        for (int s = 0; s < 4; ++s)
            STAGE2(Abuf[0], s, xs[2 * s], xs[2 * s + 1]);
        float4 b0 = *(const float4*)(xrow + 16);
        float4 b1 = *(const float4*)(xrow + 16 + 4);
        xv[0] = b0.x; xv[1] = b0.y; xv[2] = b0.z; xv[3] = b0.w;
        xv[4] = b1.x; xv[5] = b1.y; xv[6] = b1.z; xv[7] = b1.w;
    }
    i32x4 bc[2], bn[2];
    LOADB2(bc, 0);
    SOFT_BARRIER();
    i32x4 r[4], rn[4];
    READA(r, Abuf[0], 0);

    // ---- main loop: 4 K=32 steps/chunk, fine interleave, soft barrier ----
    #pragma unroll 1
    for (int c = 0; c < NCHUNK; ++c) {
        const unsigned char (*A)[128] = Abuf[c & 1];
        unsigned char (*ANX)[128]     = Abuf[(c & 1) ^ 1];
        const bool stage = (c < NCHUNK - 1);
        float4 xn0, xn1;
        if (c + 2 < NCHUNK) {
            xn0 = *(const float4*)(xrow + (c + 2) * 16);
            xn1 = *(const float4*)(xrow + (c + 2) * 16 + 4);
        }

        #pragma unroll
        for (int s = 0; s < NSTEP; ++s) {
            LOADB2(bn, (c * 4 + s + 1) & 63);    // wraps at end; harmless
            if (s < NSTEP - 1) READA(rn, A, s + 1);

            __builtin_amdgcn_s_setprio(1);
            #pragma unroll
            for (int rt = 0; rt < 4; ++rt) {
                acc[rt][0] = __builtin_amdgcn_mfma_i32_32x32x32_i8(
                    r[rt], bc[0], acc[rt][0], 0, 0, 0);
                acc[rt][1] = __builtin_amdgcn_mfma_i32_32x32x32_i8(
                    r[rt], bc[1], acc[rt][1], 0, 0, 0);
            }
            __builtin_amdgcn_s_setprio(0);

            if (stage) STAGE2(ANX, s, xv[2 * s], xv[2 * s + 1]);

            if (s < NSTEP - 1) { r[0] = rn[0]; r[1] = rn[1]; r[2] = rn[2]; r[3] = rn[3]; }
            bc[0] = bn[0]; bc[1] = bn[1];
        }
        if (c + 2 < NCHUNK) {
            xv[0] = xn0.x; xv[1] = xn0.y; xv[2] = xn0.z; xv[3] = xn0.w;
            xv[4] = xn1.x; xv[5] = xn1.y; xv[6] = xn1.z; xv[7] = xn1.w;
        }
        SOFT_BARRIER();
        if (c < NCHUNK - 1) READA(r, ANX, 0);    // next chunk's step-0 frags
    }

    // ---- epilogue: scale, add bias, store f32 ----
    // C/D 32x32: col = lane&31, row = (q&3) + 8*(q>>2) + 4*(lane>>5)
    #pragma unroll
    for (int ct = 0; ct < 2; ++ct) {
        const int col = w * 64 + ct * 32 + m;
        const float bv = bias[col];
        #pragma unroll
        for (int rt = 0; rt < 4; ++rt) {
            #pragma unroll
            for (int q = 0; q < 16; ++q) {
                const int grow = row0 + rt * 32 + (q & 3) + 8 * (q >> 2) + 4 * h;
                y[(size_t)grow * DIM_O + col] =
                    __builtin_fmaf((float)acc[rt][ct][q], sf, bv);
            }
        }
    }
#undef READA
#undef LOADB2
#undef STAGE2
#undef SOFT_BARRIER
}

extern "C" void kernel_launch(void* const* d_in, const int* in_sizes, int n_in,
                              void* d_out, int out_size, void* d_ws, size_t ws_size,
                              hipStream_t stream) {
    const float* x      = (const float*)d_in[0];
    const float* coeffs = (const float*)d_in[1];
    const float* bias   = (const float*)d_in[2];
    float* y = (float*)d_out;
    unsigned int* smax = (unsigned int*)d_ws;                 // 4 B scalar
    unsigned int* wp   = (unsigned int*)((char*)d_ws + 256);  // 512 KB i8 pack

    const int n_tokens = in_sizes[0] / DIM_D;     // 65536

    hipMemsetAsync(smax, 0, 4, stream);
    kmax_kernel<<<512, 256, 0, stream>>>(coeffs, smax);
    pack_w_kernel<<<512, 256, 0, stream>>>(coeffs, smax, wp);
    cfkan_kernel<<<n_tokens / BM, 256, 0, stream>>>(
        x, (const i32x4*)wp, smax, bias, y);
}

// Round 12
// 54.886 us; speedup vs baseline: 2.2303x; 1.5356x over previous
//
#include <hip/hip_runtime.h>
#include <hip/hip_bf16.h>

typedef __attribute__((ext_vector_type(4)))  int   i32x4;
typedef __attribute__((ext_vector_type(16))) int   i32x16;

#define DIM_D 256
#define DIM_O 256
#define DIM_K 8
#define BM 128
#define NCHUNK 16                 // 16 chunks of 16 d-values
#define NSTEP 4                   // 4 K=32 steps per chunk (4 d's each)
#define MAGIC 12582912.f          // 1.5 * 2^23 : fma+byte-extract = rint to int8

// ---- pack kernel: one block per output row o ----
// Per-o scale s_o = max|c[o,:,:]| (block reduce, no atomics), then quantize
// into 32x32x32 i8 MFMA B-fragment order (layout verified rounds 10/11):
// byte addr = ((s*8 + ct)*64 + lane)*16 + j, where for (o,d,k):
//   s = d>>2, ct = o>>5, lane = ((d>>1)&1)*32 + (o&31), j = (d&1)*8 + k
__global__ __launch_bounds__(256) void pack_w_kernel(
    const float* __restrict__ coeffs,
    unsigned int* __restrict__ wp,
    float* __restrict__ scales)
{
    const int o = blockIdx.x;        // 0..255
    const int d = threadIdx.x;       // 0..255
    const float* cp = coeffs + ((size_t)o * DIM_D + d) * DIM_K;
    float4 c0 = *(const float4*)cp;
    float4 c1 = *(const float4*)(cp + 4);

    float m = fmaxf(fmaxf(fmaxf(fabsf(c0.x), fabsf(c0.y)),
                          fmaxf(fabsf(c0.z), fabsf(c0.w))),
                    fmaxf(fmaxf(fabsf(c1.x), fabsf(c1.y)),
                          fmaxf(fabsf(c1.z), fabsf(c1.w))));
    #pragma unroll
    for (int i = 32; i >= 1; i >>= 1)
        m = fmaxf(m, __shfl_xor(m, i));
    __shared__ float wm[4];
    if ((d & 63) == 0) wm[d >> 6] = m;
    __syncthreads();
    const float sc = fmaxf(fmaxf(fmaxf(wm[0], wm[1]), fmaxf(wm[2], wm[3])),
                           1e-30f);
    if (d == 0) scales[o] = sc;

    const float inv = 127.0f / sc;
    unsigned f0 = __float_as_uint(__builtin_fmaf(c0.x, inv, MAGIC));
    unsigned f1 = __float_as_uint(__builtin_fmaf(c0.y, inv, MAGIC));
    unsigned f2 = __float_as_uint(__builtin_fmaf(c0.z, inv, MAGIC));
    unsigned f3 = __float_as_uint(__builtin_fmaf(c0.w, inv, MAGIC));
    unsigned f4 = __float_as_uint(__builtin_fmaf(c1.x, inv, MAGIC));
    unsigned f5 = __float_as_uint(__builtin_fmaf(c1.y, inv, MAGIC));
    unsigned f6 = __float_as_uint(__builtin_fmaf(c1.z, inv, MAGIC));
    unsigned f7 = __float_as_uint(__builtin_fmaf(c1.w, inv, MAGIC));
    unsigned rA = __builtin_amdgcn_perm(f1, f0, 0x00000400u);  // b0=q0 b1=q1
    unsigned rB = __builtin_amdgcn_perm(f3, f2, 0x00000400u);  // b0=q2 b1=q3
    unsigned rC = __builtin_amdgcn_perm(f5, f4, 0x00000400u);
    unsigned rD = __builtin_amdgcn_perm(f7, f6, 0x00000400u);
    unsigned lo = __builtin_amdgcn_perm(rB, rA, 0x05040100u);  // q0..q3
    unsigned hi = __builtin_amdgcn_perm(rD, rC, 0x05040100u);  // q4..q7

    const int base = (((d >> 2) * 8 + (o >> 5)) * 64
                      + ((d >> 1) & 1) * 32 + (o & 31)) * 4 + (d & 1) * 2;
    wp[base]     = lo;
    wp[base + 1] = hi;
}

// tanh + Chebyshev recurrence -> 8 orders quantized+packed to 2 u32
__device__ __forceinline__ void cheb_q8(float xs, unsigned int* o2) {
    float e2 = __expf(2.f * xs);
    float r  = __builtin_amdgcn_rcpf(e2 + 1.f);
    float T1 = __builtin_fmaf(-2.f, r, 1.f);
    float tx = T1 + T1;
    float T2 = __builtin_fmaf(tx, T1, -1.f);
    float T3 = __builtin_fmaf(tx, T2, -T1);
    float T4 = __builtin_fmaf(tx, T3, -T2);
    float T5 = __builtin_fmaf(tx, T4, -T3);
    float T6 = __builtin_fmaf(tx, T5, -T4);
    float T7 = __builtin_fmaf(tx, T6, -T5);
    unsigned f1 = __float_as_uint(__builtin_fmaf(T1, 127.f, MAGIC));
    unsigned f2 = __float_as_uint(__builtin_fmaf(T2, 127.f, MAGIC));
    unsigned f3 = __float_as_uint(__builtin_fmaf(T3, 127.f, MAGIC));
    unsigned f4 = __float_as_uint(__builtin_fmaf(T4, 127.f, MAGIC));
    unsigned f5 = __float_as_uint(__builtin_fmaf(T5, 127.f, MAGIC));
    unsigned f6 = __float_as_uint(__builtin_fmaf(T6, 127.f, MAGIC));
    unsigned f7 = __float_as_uint(__builtin_fmaf(T7, 127.f, MAGIC));
    unsigned rA = __builtin_amdgcn_perm(f2, f1, 0x00000400u);  // b0=q1 b1=q2
    unsigned rC = __builtin_amdgcn_perm(f5, f4, 0x00000400u);  // b0=q4 b1=q5
    unsigned rD = __builtin_amdgcn_perm(f7, f6, 0x00000400u);  // b0=q6 b1=q7
    // o2[0] = 127 | q1<<8 | q2<<16 | q3<<24  (sel 0x0c -> 0x00, then |127)
    o2[0] = __builtin_amdgcn_perm(f3, rA, 0x0401000Cu) | 127u;
    o2[1] = __builtin_amdgcn_perm(rD, rC, 0x05040100u);        // q4..q7
}

__global__ __launch_bounds__(256, 2) void cfkan_kernel(
    const float* __restrict__ x,
    const i32x4* __restrict__ wp8,
    const float* __restrict__ scales,
    const float* __restrict__ bias,
    float* __restrict__ y)
{
    // double-buffered i8 A tile: [row][8 slots of 16B], slot XOR-swizzle; 32 KB
    __shared__ unsigned char Abuf[2][BM][128];

    const int t = threadIdx.x;
    const int w = t >> 6;            // wave 0..3 -> output cols [64w, 64w+64)
    const int l = t & 63;
    const int m = l & 31;            // A row / B,C col within 32-tile
    const int h = l >> 5;            // k-half: d-pair parity
    const int row0 = blockIdx.x * BM;

    i32x16 acc[4][2];
    #pragma unroll
    for (int rt = 0; rt < 4; ++rt)
        #pragma unroll
        for (int ct = 0; ct < 2; ++ct)
            #pragma unroll
            for (int q = 0; q < 16; ++q)
                acc[rt][ct][q] = 0;

    const int lrow = t >> 1;         // 0..127 (row this thread stages)
    const int half = t & 1;          // which 8 of the 16 chunk-d's
    const float* xrow = x + (size_t)(row0 + lrow) * DIM_D + half * 8;

// A-frag read: step S, lane -> rows rt*32+m, slot (2S+h), XOR by row&7
#define READA(DST, AB, S) do {                                             \
    const int _so = (((2 * (S) + h) ^ (m & 7)) * 16);                      \
    DST[0] = *(const i32x4*)&AB[      m][_so];                             \
    DST[1] = *(const i32x4*)&AB[ 32 + m][_so];                             \
    DST[2] = *(const i32x4*)&AB[ 64 + m][_so];                             \
    DST[3] = *(const i32x4*)&AB[ 96 + m][_so];                             \
} while (0)
#define LOADB2(DST, SG) do {                                               \
    DST[0] = wp8[((SG) * 8 + w * 2 + 0) * 64 + l];                         \
    DST[1] = wp8[((SG) * 8 + w * 2 + 1) * 64 + l];                         \
} while (0)
// stage d-pair {2S, 2S+1} of next chunk: one swizzled ds_write_b128
#define STAGE2(ANX, S, X0, X1) do {                                        \
    union { unsigned int u[4]; i32x4 v; } _tv;                             \
    cheb_q8(X0, &_tv.u[0]);                                                \
    cheb_q8(X1, &_tv.u[2]);                                                \
    *(i32x4*)&ANX[lrow][(((half * 4 + (S)) ^ (lrow & 7)) * 16)] = _tv.v;   \
} while (0)
// barrier draining ONLY LDS ops; global loads stay in flight (T4)
#define SOFT_BARRIER() do {                                                \
    asm volatile("s_waitcnt lgkmcnt(0)" ::: "memory");                     \
    __builtin_amdgcn_s_barrier();                                          \
    __builtin_amdgcn_sched_barrier(0);                                     \
} while (0)

    // ---- prologue: stage chunk 0; preload x(chunk1) + B(step0) ----
    float xv[8];
    {
        float4 a0 = *(const float4*)xrow;
        float4 a1 = *(const float4*)(xrow + 4);
        float xs[8] = {a0.x, a0.y, a0.z, a0.w, a1.x, a1.y, a1.z, a1.w};
        #pragma unroll
        for (int s = 0; s < 4; ++s)
            STAGE2(Abuf[0], s, xs[2 * s], xs[2 * s + 1]);
        float4 b0 = *(const float4*)(xrow + 16);
        float4 b1 = *(const float4*)(xrow + 16 + 4);
        xv[0] = b0.x; xv[1] = b0.y; xv[2] = b0.z; xv[3] = b0.w;
        xv[4] = b1.x; xv[5] = b1.y; xv[6] = b1.z; xv[7] = b1.w;
    }
    i32x4 bc[2], bn[2];
    LOADB2(bc, 0);
    SOFT_BARRIER();
    i32x4 r[4], rn[4];
    READA(r, Abuf[0], 0);

    // ---- main loop: 4 K=32 steps/chunk, fine interleave, soft barrier ----
    #pragma unroll 1
    for (int c = 0; c < NCHUNK; ++c) {
        const unsigned char (*A)[128] = Abuf[c & 1];
        unsigned char (*ANX)[128]     = Abuf[(c & 1) ^ 1];
        const bool stage = (c < NCHUNK - 1);
        float4 xn0, xn1;
        if (c + 2 < NCHUNK) {
            xn0 = *(const float4*)(xrow + (c + 2) * 16);
            xn1 = *(const float4*)(xrow + (c + 2) * 16 + 4);
        }

        #pragma unroll
        for (int s = 0; s < NSTEP; ++s) {
            LOADB2(bn, (c * 4 + s + 1) & 63);    // wraps at end; harmless
            if (s < NSTEP - 1) READA(rn, A, s + 1);

            __builtin_amdgcn_s_setprio(1);
            #pragma unroll
            for (int rt = 0; rt < 4; ++rt) {
                acc[rt][0] = __builtin_amdgcn_mfma_i32_32x32x32_i8(
                    r[rt], bc[0], acc[rt][0], 0, 0, 0);
                acc[rt][1] = __builtin_amdgcn_mfma_i32_32x32x32_i8(
                    r[rt], bc[1], acc[rt][1], 0, 0, 0);
            }
            __builtin_amdgcn_s_setprio(0);

            if (stage) STAGE2(ANX, s, xv[2 * s], xv[2 * s + 1]);

            if (s < NSTEP - 1) { r[0] = rn[0]; r[1] = rn[1]; r[2] = rn[2]; r[3] = rn[3]; }
            bc[0] = bn[0]; bc[1] = bn[1];
        }
        if (c + 2 < NCHUNK) {
            xv[0] = xn0.x; xv[1] = xn0.y; xv[2] = xn0.z; xv[3] = xn0.w;
            xv[4] = xn1.x; xv[5] = xn1.y; xv[6] = xn1.z; xv[7] = xn1.w;
        }
        SOFT_BARRIER();
        if (c < NCHUNK - 1) READA(r, ANX, 0);    // next chunk's step-0 frags
    }

    // ---- epilogue: per-column scale, add bias, store f32 ----
    // C/D 32x32: col = lane&31, row = (q&3) + 8*(q>>2) + 4*(lane>>5)
    #pragma unroll
    for (int ct = 0; ct < 2; ++ct) {
        const int col = w * 64 + ct * 32 + m;
        const float sf = scales[col] * (1.f / 16129.f);   // s_o / 127^2
        const float bv = bias[col];
        #pragma unroll
        for (int rt = 0; rt < 4; ++rt) {
            #pragma unroll
            for (int q = 0; q < 16; ++q) {
                const int grow = row0 + rt * 32 + (q & 3) + 8 * (q >> 2) + 4 * h;
                y[(size_t)grow * DIM_O + col] =
                    __builtin_fmaf((float)acc[rt][ct][q], sf, bv);
            }
        }
    }
#undef READA
#undef LOADB2
#undef STAGE2
#undef SOFT_BARRIER
}

extern "C" void kernel_launch(void* const* d_in, const int* in_sizes, int n_in,
                              void* d_out, int out_size, void* d_ws, size_t ws_size,
                              hipStream_t stream) {
    const float* x      = (const float*)d_in[0];
    const float* coeffs = (const float*)d_in[1];
    const float* bias   = (const float*)d_in[2];
    float* y = (float*)d_out;
    float*        scales = (float*)d_ws;                      // 1 KB
    unsigned int* wp     = (unsigned int*)((char*)d_ws + 1024); // 512 KB

    const int n_tokens = in_sizes[0] / DIM_D;     // 65536

    pack_w_kernel<<<DIM_O, 256, 0, stream>>>(coeffs, wp, scales);
    cfkan_kernel<<<n_tokens / BM, 256, 0, stream>>>(
        x, (const i32x4*)wp, scales, bias, y);
}